// Round 8
// baseline (161.059 us; speedup 1.0000x reference)
//
#include <hip/hip_runtime.h>
#include <hip/hip_bf16.h>

#define BS 16
#define TT 20
#define STEPS 12
#define NN 512
#define EE 64

typedef __attribute__((ext_vector_type(8))) short bfrag8;
typedef __attribute__((ext_vector_type(4))) float f32x4;
typedef unsigned short ushort_t;
typedef unsigned int uint_t;

#define MFMA16(a,b,c) __builtin_amdgcn_mfma_f32_16x16x32_bf16(a,b,c,0,0,0)

#if __has_builtin(__builtin_amdgcn_rcpf)
#define RCP(x) __builtin_amdgcn_rcpf(x)
#else
#define RCP(x) (1.0f/(x))
#endif

#if __has_builtin(__builtin_amdgcn_exp2f)
#define EXP2F(x) __builtin_amdgcn_exp2f(x)
#else
#define EXP2F(x) exp2f(x)
#endif

// tanh(x) = 1 - 2/(1+e^{2x}); 5 VALU ops, full-range safe.
__device__ __forceinline__ float tanh_fast(float x) {
  float t = EXP2F(x * 2.8853900817779268f);   // e^{2x}
  return 1.f - 2.f * RCP(1.f + t);
}

__device__ __forceinline__ float lrelu(float x) { return x > 0.f ? x : 0.01f * x; }

__device__ __forceinline__ float wsum64(float x) {
  #pragma unroll
  for (int off = 32; off > 0; off >>= 1) x += __shfl_xor(x, off);
  return x;
}

__device__ __forceinline__ ushort_t f2bf(float f) {   // RNE float->bf16
  uint_t u = __float_as_uint(f);
  u += 0x7fffu + ((u >> 16) & 1u);
  return (ushort_t)(u >> 16);
}

// Pade combine: tanh(u+v) = (tu+tv)/(1+tu*tv), 2 elems -> packed bf16x2
__device__ __forceinline__ __hip_bfloat162 pade2(float2 tv, float2 tu) {
  float nx = tu.x + tv.x, ny = tu.y + tv.y;
  float dx = fmaf(tu.x, tv.x, 1.f), dy = fmaf(tu.y, tv.y, 1.f);
  dx = fmaxf(dx, 1e-30f); dy = fmaxf(dy, 1e-30f);
  float2 m; m.x = nx * RCP(dx); m.y = ny * RCP(dy);
  return __float22bfloat162_rn(m);
}

// ===========================================================================
// setup: crow[kb][tpos][p] = adj[kb][sk[tpos]][node_p]
//                          + (1/512) sum_m adj[kb][sk[tpos]][m] adj[kb][m][node_p]
// grid 128 = kb(32) x pq(4, 5 columns each), 256 threads.
// Column gather (stride-2048, latency-heavy) issued FIRST, overlapping the
// coalesced row staging; s_node LDS round-trip + barrier removed.
// ===========================================================================
__global__ __launch_bounds__(256) void setup_kernel(
    const int* __restrict__ skill, const float* __restrict__ adj,
    float* __restrict__ crow)
{
  __shared__ __align__(16) float a_rows[19*516];
  __shared__ __align__(16) float a_cols[5*516];
  __shared__ float red[95*2];

  int tid = threadIdx.x, bid = blockIdx.x;
  int kb = bid >> 2, pq = bid & 3;
  int b = kb & 15;
  const float* A = adj + (size_t)kb*NN*NN;

  // scattered column gather first (node index read straight from skill)
  for (int idx = tid; idx < 5*512; idx += 256) {
    int p = idx >> 9, m = idx & 511;
    a_cols[p*516 + m] = A[(size_t)m*NN + skill[b*TT + pq*5 + p]];
  }
  // coalesced row staging second (overlaps with in-flight gathers)
  for (int idx = tid; idx < 19*512; idx += 256) {
    int tpos = idx >> 9, m = idx & 511;
    a_rows[tpos*516 + m] = A[(size_t)skill[b*TT + tpos]*NN + m];
  }
  __syncthreads();

  int pr = tid & 127, mh = tid >> 7;
  if (pr < 95) {
    int tpos = pr / 5, p = pr % 5;
    const float4* ra = (const float4*)&a_rows[tpos*516 + mh*256];
    const float4* rc = (const float4*)&a_cols[p*516 + mh*256];
    float s = 0.f;
    #pragma unroll 8
    for (int i = 0; i < 64; ++i) {
      float4 x = ra[i], y = rc[i];
      s += x.x*y.x + x.y*y.y + x.z*y.z + x.w*y.w;
    }
    red[pr*2 + mh] = s;
  }
  __syncthreads();
  if (tid < 95) {
    int tpos = tid / 5, p = tid % 5;
    float dot = red[tid*2] + red[tid*2 + 1];
    crow[(size_t)kb*380 + tpos*20 + pq*5 + p] =
        a_rows[tpos*516 + skill[b*TT + pq*5 + p]] + dot * (1.f/512.f);
  }
}

// ===========================================================================
// step+head, one block (512 thr, 8 warps) per batch.
// Phase A (pruned+balanced): only rows >= t are live.  Single 16-row A-tile
// (rows t..t+15; zero-rows 20..31 pad) projected by all 8 warps:
// warps 0-3 -> v = tanh(W1b h) col-group w; warps 4-7 -> u = tanh(W1a h + b1)
// col-group w-4.  2 MFMAs + <=4 tanh per warp.  t<4: v-warps do one extra
// tile for rows t+16..19.
// Phase B: per-warp tiles, in-register Pade -> 8 MFMAs -> tanh*ed -> crow
// reduce -> sH rows [t+1,19] (t=11: {19}).  Head on prestaged LDS weights.
// ===========================================================================
__global__ __launch_bounds__(512) void step_kernel(
    const int* __restrict__ skill, const int* __restrict__ timeq,
    const int* __restrict__ label, const float* __restrict__ nemb,
    const float* __restrict__ W1, const float* __restrict__ W2,
    const float* __restrict__ b1, const float* __restrict__ b2,
    const float* __restrict__ crow,
    const float* __restrict__ fw1, const float* __restrict__ fb1,
    const float* __restrict__ g1, const float* __restrict__ be1,
    const float* __restrict__ fw2, const float* __restrict__ fb2,
    const float* __restrict__ g2, const float* __restrict__ be2,
    const float* __restrict__ fw3, const float* __restrict__ fb3,
    float* __restrict__ out)
{
  __shared__ __align__(16) ushort_t sWa[64*72];
  __shared__ __align__(16) ushort_t sWb[64*72];
  __shared__ __align__(16) ushort_t sW2[64*72];
  __shared__ __align__(16) ushort_t sH[32*72];     // rows 0..19 hidden, 20..31 zero
  __shared__ __align__(16) float sTV[20*72];
  __shared__ __align__(16) float sTU[8*72];
  __shared__ float sCROW[2*19*20];                 // [k][tpos][p]
  __shared__ float sED[STEPS*8];
  __shared__ float sAGG[24*68];                    // [t*2+k][e]
  __shared__ float sXN[24*68];
  __shared__ __align__(16) float fwL1[64*66];
  __shared__ __align__(16) float fwL2[64*66];
  __shared__ int sSK[TT];

  int tid = threadIdx.x, b = blockIdx.x;
  int w = tid >> 6, lane = tid & 63, q = lane >> 4, nn = lane & 15;
  int ct = w & 3, epos = ct*16 + nn;

  if (tid < TT) sSK[tid] = skill[b*TT + tid];
  for (int idx = tid; idx < 4096; idx += 512) {
    int e = idx >> 6, j = idx & 63;
    sWa[e*72 + j] = f2bf(W1[e*128 + j]);         // hh side (u)
    sWb[e*72 + j] = f2bf(W1[e*128 + 64 + j]);    // hidden side (v)
    sW2[e*72 + j] = f2bf(W2[e*64 + j]);
    fwL1[e*66 + j] = fw1[idx];
    fwL2[e*66 + j] = fw2[idx];
  }
  for (int idx = tid; idx < 760; idx += 512)
    sCROW[idx] = crow[(size_t)((idx/380)*BS + b)*380 + (idx%380)];
  if (tid < STEPS*8) {
    int s = tid >> 3, l = tid & 7;
    float d = fabsf((float)(timeq[b*TT + s + l] - timeq[b*TT + s + 8]));
    sED[tid] = expf(-logf(d + 1e-6f) * 0.6213349345596119f);
  }
  __syncthreads();                 // sSK / weights visible

  // h0: scatter-init restricted to tracked positions
  for (int idx = tid; idx < 32*64; idx += 512) {
    int p = idx >> 6, e = idx & 63;
    ushort_t hv = 0;
    if (p < 20) {
      int node = sSK[p];
      int lstar = -1;
      #pragma unroll
      for (int l = 0; l < 8; ++l) if (sSK[l] == node) lstar = l;
      if (lstar >= 0) {
        float lp = (label[b*TT + lstar] == 1) ? 1.f : -1.f;
        hv = f2bf(nemb[node*EE + e] * lp);
      }
    }
    sH[p*72 + e] = hv;
  }
  __syncthreads();

  // constant-per-thread fragments
  const ushort_t* WAB = (w < 4) ? sWb : sWa;     // phase-A B operand per warp
  bfrag8 wab0 = *(const bfrag8*)&WAB[epos*72 + q*8];
  bfrag8 wab1 = *(const bfrag8*)&WAB[epos*72 + 32 + q*8];
  bfrag8 w200 = *(const bfrag8*)&sW2[(0*16+nn)*72 + q*8];
  bfrag8 w201 = *(const bfrag8*)&sW2[(0*16+nn)*72 + 32 + q*8];
  bfrag8 w210 = *(const bfrag8*)&sW2[(1*16+nn)*72 + q*8];
  bfrag8 w211 = *(const bfrag8*)&sW2[(1*16+nn)*72 + 32 + q*8];
  bfrag8 w220 = *(const bfrag8*)&sW2[(2*16+nn)*72 + q*8];
  bfrag8 w221 = *(const bfrag8*)&sW2[(2*16+nn)*72 + 32 + q*8];
  bfrag8 w230 = *(const bfrag8*)&sW2[(3*16+nn)*72 + q*8];
  bfrag8 w231 = *(const bfrag8*)&sW2[(3*16+nn)*72 + 32 + q*8];
  float b1v = b1[epos];
  float b2v0 = b2[nn], b2v1 = b2[16+nn], b2v2 = b2[32+nn], b2v3 = b2[48+nn];
  const bfrag8 ZB = {0,0,0,0,0,0,0,0};

  for (int t = 0; t < STEPS; ++t) {
    int p0 = (t == 11) ? 19 : t + 1;
    int R  = (t == 11) ? 1  : 19 - t;
    int ntiles = (R + 1) >> 1;

    // ---- phase A (pruned, balanced): tile rows t..t+15
    {
      bfrag8 a0 = *(const bfrag8*)&sH[(t + nn)*72 + q*8];
      bfrag8 a1 = *(const bfrag8*)&sH[(t + nn)*72 + 32 + q*8];
      f32x4 acc = {0,0,0,0};
      acc = MFMA16(a0, wab0, acc);
      acc = MFMA16(a1, wab1, acc);
      if (w < 4) {                       // v-projection
        #pragma unroll
        for (int r = 0; r < 4; ++r) {
          int ar = q*4 + r;
          if (t + ar <= 19) sTV[(t + ar)*72 + epos] = tanh_fast(acc[r]);
        }
        if (t < 4) {                     // tile1: rows t+16..19
          int rr = t + 16 + nn; if (rr > 19) rr = 24;   // 24.. are zero
          bfrag8 c0 = *(const bfrag8*)&sH[rr*72 + q*8];
          bfrag8 c1 = *(const bfrag8*)&sH[rr*72 + 32 + q*8];
          f32x4 acc2 = {0,0,0,0};
          acc2 = MFMA16(c0, wab0, acc2);
          acc2 = MFMA16(c1, wab1, acc2);
          #pragma unroll
          for (int r = 0; r < 4; ++r) {
            int ar = 16 + q*4 + r;
            if (t + ar <= 19) sTV[(t + ar)*72 + epos] = tanh_fast(acc2[r]);
          }
        }
      } else if (q < 2) {                // u-projection, rows l=0..7 only
        #pragma unroll
        for (int r = 0; r < 4; ++r)
          sTU[(q*4 + r)*72 + epos] = tanh_fast(acc[r] + b1v);
      }
    }
    __syncthreads();

    // ---- phase B: per-warp whole tiles, in-register Pade -> MFMA -> epilogue
    for (int rt = w; rt < ntiles; rt += 8) {
      int i = rt*2 + (nn >> 3);       // A-row block (relative p index)
      int lA = nn & 7;
      bfrag8 a0 = ZB, a1 = ZB;
      if (i < R) {
        int p = p0 + i;
        const float2* tvlo = (const float2*)&sTV[p*72 + q*8];
        const float2* tvhi = (const float2*)&sTV[p*72 + 32 + q*8];
        const float2* tulo = (const float2*)&sTU[lA*72 + q*8];
        const float2* tuhi = (const float2*)&sTU[lA*72 + 32 + q*8];
        union { bfrag8 v; __hip_bfloat162 h[4]; } A0, A1;
        #pragma unroll
        for (int j = 0; j < 4; ++j) {
          A0.h[j] = pade2(tvlo[j], tulo[j]);
          A1.h[j] = pade2(tvhi[j], tuhi[j]);
        }
        a0 = A0.v; a1 = A1.v;
      }
      f32x4 z0 = {0,0,0,0}, z1 = {0,0,0,0}, z2 = {0,0,0,0}, z3 = {0,0,0,0};
      z0 = MFMA16(a0, w200, z0);  z0 = MFMA16(a1, w201, z0);
      z1 = MFMA16(a0, w210, z1);  z1 = MFMA16(a1, w211, z1);
      z2 = MFMA16(a0, w220, z2);  z2 = MFMA16(a1, w221, z2);
      z3 = MFMA16(a0, w230, z3);  z3 = MFMA16(a1, w231, z3);

      int pi = rt*2 + (q >> 1);       // D-row block (relative p index)
      int p = p0 + pi;
      int psafe = (pi < R) ? p : p0;  // keep LDS reads in range
      float ag00=0,ag01=0,ag02=0,ag03=0, ag10=0,ag11=0,ag12=0,ag13=0;
      #pragma unroll
      for (int r = 0; r < 4; ++r) {
        int l = (q & 1)*4 + r;
        float c0 = sCROW[(t + l)*20 + psafe];
        float c1 = sCROW[380 + (t + l)*20 + psafe];
        float ed = sED[t*8 + l];
        float m;
        m = tanh_fast(z0[r] + b2v0) * ed; ag00 = fmaf(c0,m,ag00); ag10 = fmaf(c1,m,ag10);
        m = tanh_fast(z1[r] + b2v1) * ed; ag01 = fmaf(c0,m,ag01); ag11 = fmaf(c1,m,ag11);
        m = tanh_fast(z2[r] + b2v2) * ed; ag02 = fmaf(c0,m,ag02); ag12 = fmaf(c1,m,ag12);
        m = tanh_fast(z3[r] + b2v3) * ed; ag03 = fmaf(c0,m,ag03); ag13 = fmaf(c1,m,ag13);
      }
      ag00 += __shfl_xor(ag00,16); ag01 += __shfl_xor(ag01,16);
      ag02 += __shfl_xor(ag02,16); ag03 += __shfl_xor(ag03,16);
      ag10 += __shfl_xor(ag10,16); ag11 += __shfl_xor(ag11,16);
      ag12 += __shfl_xor(ag12,16); ag13 += __shfl_xor(ag13,16);
      if ((q & 1) == 0 && pi < R) {
        sH[p*72 +      nn] = f2bf(0.5f*(ag00 + ag10));
        sH[p*72 + 16 + nn] = f2bf(0.5f*(ag01 + ag11));
        sH[p*72 + 32 + nn] = f2bf(0.5f*(ag02 + ag12));
        sH[p*72 + 48 + nn] = f2bf(0.5f*(ag03 + ag13));
        if (p == t + 8) {
          sAGG[(t*2 + 0)*68 +      nn] = ag00;
          sAGG[(t*2 + 0)*68 + 16 + nn] = ag01;
          sAGG[(t*2 + 0)*68 + 32 + nn] = ag02;
          sAGG[(t*2 + 0)*68 + 48 + nn] = ag03;
          sAGG[(t*2 + 1)*68 +      nn] = ag10;
          sAGG[(t*2 + 1)*68 + 16 + nn] = ag11;
          sAGG[(t*2 + 1)*68 + 32 + nn] = ag12;
          sAGG[(t*2 + 1)*68 + 48 + nn] = ag13;
        }
      }
    }
    __syncthreads();
  }

  // ======================= head (fused pred) =======================
  // 24 tasks = (t,k); task = round*8 + w; weights prestaged in fwL1/fwL2.
  int e = lane;
  float h1s[3];
  float fb1v = fb1[e], g1v = g1[e], be1v = be1[e];
  #pragma unroll
  for (int r3 = 0; r3 < 3; ++r3) {
    int task = r3*8 + w;
    const float* xv = &sAGG[task*68];
    const float2* xv2 = (const float2*)xv;
    const float2* wp  = (const float2*)&fwL1[e*66];
    float x = xv[e];
    float y0 = fb1v, y1 = 0.f;
    #pragma unroll
    for (int j = 0; j < 32; j += 2) {
      float2 a  = xv2[j];     float2 bb = wp[j];
      y0 = fmaf(a.x, bb.x, y0);  y0 = fmaf(a.y, bb.y, y0);
      float2 a2 = xv2[j+1];   float2 b2f = wp[j+1];
      y1 = fmaf(a2.x, b2f.x, y1);  y1 = fmaf(a2.y, b2f.y, y1);
    }
    float h1 = x + lrelu(y0 + y1);
    float mean1 = wsum64(h1) * (1.f/64.f);
    float d1 = h1 - mean1;
    float var1 = wsum64(d1*d1) * (1.f/64.f);
    float xn = d1 * rsqrtf(var1 + 1e-5f) * g1v + be1v;
    sXN[task*68 + e] = xn;
    h1s[r3] = h1;
  }
  __syncthreads();                 // all xn written

  float fb2v = fb2[e], g2v = g2[e], be2v = be2[e];
  float w3a = fw3[e], w3b = fw3[64 + e];
  float fb30 = fb3[0], fb31 = fb3[1];
  #pragma unroll
  for (int r3 = 0; r3 < 3; ++r3) {
    int task = r3*8 + w;
    const float2* xn2v = (const float2*)&sXN[task*68];
    const float2* wp   = (const float2*)&fwL2[e*66];
    float z0 = fb2v, z1 = 0.f;
    #pragma unroll
    for (int j = 0; j < 32; j += 2) {
      float2 a  = xn2v[j];    float2 bb = wp[j];
      z0 = fmaf(a.x, bb.x, z0);  z0 = fmaf(a.y, bb.y, z0);
      float2 a2 = xn2v[j+1];  float2 b2f = wp[j+1];
      z1 = fmaf(a2.x, b2f.x, z1);  z1 = fmaf(a2.y, b2f.y, z1);
    }
    float h2 = h1s[r3] + lrelu(z0 + z1);
    float mean2 = wsum64(h2) * (1.f/64.f);
    float d2 = h2 - mean2;
    float var2 = wsum64(d2*d2) * (1.f/64.f);
    float xn2 = d2 * rsqrtf(var2 + 1e-5f) * g2v + be2v;
    float p0s = wsum64(xn2 * w3a);
    float p1s = wsum64(xn2 * w3b);
    if (e == 0) {
      int ts = task >> 1, kk = task & 1;
      float l0 = p0s + fb30, l1 = p1s + fb31;
      out[(ts*BS + b)*2 + kk] = 1.f / (1.f + expf(l0 - l1));
    }
  }
}

extern "C" void kernel_launch(void* const* d_in, const int* in_sizes, int n_in,
                              void* d_out, int out_size, void* d_ws, size_t ws_size,
                              hipStream_t stream) {
  const int*   skill = (const int*)d_in[0];
  const int*   timeq = (const int*)d_in[1];
  const int*   label = (const int*)d_in[2];
  const float* adj   = (const float*)d_in[3];
  const float* nemb  = (const float*)d_in[4];
  const float* W1    = (const float*)d_in[5];
  const float* b1    = (const float*)d_in[6];
  const float* W2    = (const float*)d_in[7];
  const float* b2    = (const float*)d_in[8];
  float* out = (float*)d_out;

  float* crow = (float*)d_ws;                // 32*19*20 = 12160 floats

  setup_kernel<<<128, 256, 0, stream>>>(skill, adj, crow);
  step_kernel<<<16, 512, 0, stream>>>(skill, timeq, label, nemb, W1, W2,
      b1, b2, crow,
      (const float*)d_in[9],  (const float*)d_in[10],
      (const float*)d_in[11], (const float*)d_in[12],
      (const float*)d_in[13], (const float*)d_in[14],
      (const float*)d_in[15], (const float*)d_in[16],
      (const float*)d_in[17], (const float*)d_in[18], out);
}

// Round 9
// 157.809 us; speedup vs baseline: 1.0206x; 1.0206x over previous
//
#include <hip/hip_runtime.h>
#include <hip/hip_bf16.h>

#define BS 16
#define TT 20
#define STEPS 12
#define NN 512
#define EE 64

typedef __attribute__((ext_vector_type(8))) short bfrag8;
typedef __attribute__((ext_vector_type(4))) float f32x4;
typedef unsigned short ushort_t;
typedef unsigned int uint_t;

#define MFMA16(a,b,c) __builtin_amdgcn_mfma_f32_16x16x32_bf16(a,b,c,0,0,0)

#if __has_builtin(__builtin_amdgcn_rcpf)
#define RCP(x) __builtin_amdgcn_rcpf(x)
#else
#define RCP(x) (1.0f/(x))
#endif

#if __has_builtin(__builtin_amdgcn_exp2f)
#define EXP2F(x) __builtin_amdgcn_exp2f(x)
#else
#define EXP2F(x) exp2f(x)
#endif

// tanh(x) = 1 - 2/(1+e^{2x}); 5 VALU ops, full-range safe.
__device__ __forceinline__ float tanh_fast(float x) {
  float t = EXP2F(x * 2.8853900817779268f);   // e^{2x}
  return 1.f - 2.f * RCP(1.f + t);
}

__device__ __forceinline__ float lrelu(float x) { return x > 0.f ? x : 0.01f * x; }

__device__ __forceinline__ float wsum64(float x) {
  #pragma unroll
  for (int off = 32; off > 0; off >>= 1) x += __shfl_xor(x, off);
  return x;
}

__device__ __forceinline__ ushort_t f2bf(float f) {   // RNE float->bf16
  uint_t u = __float_as_uint(f);
  u += 0x7fffu + ((u >> 16) & 1u);
  return (ushort_t)(u >> 16);
}

// Pade combine: tanh(u+v) = (tu+tv)/(1+tu*tv), 2 elems -> packed bf16x2
__device__ __forceinline__ __hip_bfloat162 pade2(float2 tv, float2 tu) {
  float nx = tu.x + tv.x, ny = tu.y + tv.y;
  float dx = fmaf(tu.x, tv.x, 1.f), dy = fmaf(tu.y, tv.y, 1.f);
  dx = fmaxf(dx, 1e-30f); dy = fmaxf(dy, 1e-30f);
  float2 m; m.x = nx * RCP(dx); m.y = ny * RCP(dy);
  return __float22bfloat162_rn(m);
}

// ===========================================================================
// setup: crow[kb][tpos][p] = adj[kb][sk[tpos]][node_p]
//                          + (1/512) sum_m adj[kb][sk[tpos]][m] adj[kb][m][node_p]
// grid 128 = kb(32) x pq(4, 5 columns each), 256 threads.
// (round-7 form — best measured; gather needs the 128-block MLP spread)
// ===========================================================================
__global__ __launch_bounds__(256) void setup_kernel(
    const int* __restrict__ skill, const float* __restrict__ adj,
    float* __restrict__ crow)
{
  __shared__ __align__(16) float a_rows[19*516];
  __shared__ __align__(16) float a_cols[5*516];
  __shared__ float red[95*2];
  __shared__ int s_node[5];

  int tid = threadIdx.x, bid = blockIdx.x;
  int kb = bid >> 2, pq = bid & 3;
  int b = kb & 15;
  const float* A = adj + (size_t)kb*NN*NN;

  for (int idx = tid; idx < 19*512; idx += 256) {
    int tpos = idx >> 9, m = idx & 511;
    a_rows[tpos*516 + m] = A[(size_t)skill[b*TT + tpos]*NN + m];
  }
  if (tid < 5) s_node[tid] = skill[b*TT + pq*5 + tid];
  __syncthreads();
  for (int idx = tid; idx < 5*512; idx += 256) {
    int p = idx >> 9, m = idx & 511;
    a_cols[p*516 + m] = A[(size_t)m*NN + s_node[p]];
  }
  __syncthreads();

  int pr = tid & 127, mh = tid >> 7;
  if (pr < 95) {
    int tpos = pr / 5, p = pr % 5;
    const float4* ra = (const float4*)&a_rows[tpos*516 + mh*256];
    const float4* rc = (const float4*)&a_cols[p*516 + mh*256];
    float s = 0.f;
    #pragma unroll 8
    for (int i = 0; i < 64; ++i) {
      float4 x = ra[i], y = rc[i];
      s += x.x*y.x + x.y*y.y + x.z*y.z + x.w*y.w;
    }
    red[pr*2 + mh] = s;
  }
  __syncthreads();
  if (tid < 95) {
    int tpos = tid / 5, p = tid % 5;
    float dot = red[tid*2] + red[tid*2 + 1];
    crow[(size_t)kb*380 + tpos*20 + pq*5 + p] =
        a_rows[tpos*516 + s_node[p]] + dot * (1.f/512.f);
  }
}

// ===========================================================================
// step+head, one block (512 thr, 8 warps) per batch.  Round-7 structure
// (best measured) with VECTORIZED init staging (float4/float2/short4).
// Per step (2 barriers): phase A = GEMM1 -> tanh(v) rows 0..19, tanh(u) l 0..7;
// phase B = per-warp whole tiles: in-register Pade -> 8 MFMAs -> tanh*ed ->
// crow l-reduce -> sH rows [t+1,19].  Head on prestaged LDS weights.
// ===========================================================================
__global__ __launch_bounds__(512) void step_kernel(
    const int* __restrict__ skill, const int* __restrict__ timeq,
    const int* __restrict__ label, const float* __restrict__ nemb,
    const float* __restrict__ W1, const float* __restrict__ W2,
    const float* __restrict__ b1, const float* __restrict__ b2,
    const float* __restrict__ crow,
    const float* __restrict__ fw1, const float* __restrict__ fb1,
    const float* __restrict__ g1, const float* __restrict__ be1,
    const float* __restrict__ fw2, const float* __restrict__ fb2,
    const float* __restrict__ g2, const float* __restrict__ be2,
    const float* __restrict__ fw3, const float* __restrict__ fb3,
    float* __restrict__ out)
{
  __shared__ __align__(16) ushort_t sWa[64*72];
  __shared__ __align__(16) ushort_t sWb[64*72];
  __shared__ __align__(16) ushort_t sW2[64*72];
  __shared__ __align__(16) ushort_t sH[32*72];     // rows 0..19 hidden, 20..31 zero
  __shared__ __align__(16) float sTV[20*72];
  __shared__ __align__(16) float sTU[8*72];
  __shared__ __align__(16) float sCROW[2*19*20];   // [k][tpos][p]
  __shared__ float sED[STEPS*8];
  __shared__ float sAGG[24*68];                    // [t*2+k][e]
  __shared__ float sXN[24*68];
  __shared__ __align__(16) float fwL1[64*66];
  __shared__ __align__(16) float fwL2[64*66];
  __shared__ int sSK[TT];

  int tid = threadIdx.x, b = blockIdx.x;
  int w = tid >> 6, lane = tid & 63, q = lane >> 4, nn = lane & 15;
  int ct = w & 3, half = w >> 2, epos = ct*16 + nn;

  if (tid < TT) sSK[tid] = skill[b*TT + tid];

  // ---- vectorized staging (bit-identical values to scalar form) ----
  // W1 [64][128] -> sWa (cols 0..63) / sWb (cols 64..127), bf16
  for (int idx = tid; idx < 2048; idx += 512) {
    int e = idx >> 5, j4 = idx & 31;               // j = j4*4
    float4 v = *(const float4*)&W1[e*128 + j4*4];
    short4 s;
    s.x = (short)f2bf(v.x); s.y = (short)f2bf(v.y);
    s.z = (short)f2bf(v.z); s.w = (short)f2bf(v.w);
    ushort_t* dst = (j4 < 16) ? &sWa[e*72 + j4*4] : &sWb[e*72 + (j4 - 16)*4];
    *(short4*)dst = s;
  }
  // W2 [64][64] -> sW2 bf16
  for (int idx = tid; idx < 1024; idx += 512) {
    int e = idx >> 4, j4 = idx & 15;
    float4 v = *(const float4*)&W2[e*64 + j4*4];
    short4 s;
    s.x = (short)f2bf(v.x); s.y = (short)f2bf(v.y);
    s.z = (short)f2bf(v.z); s.w = (short)f2bf(v.w);
    *(short4*)&sW2[e*72 + j4*4] = s;
  }
  // fw1/fw2 f32 -> LDS (stride 66; float2 stores keep 8B alignment for all e)
  for (int idx = tid; idx < 2048; idx += 512) {
    int e = idx >> 5, j2 = idx & 31;               // j = j2*2
    *(float2*)&fwL1[e*66 + j2*2] = *(const float2*)&fw1[e*64 + j2*2];
    *(float2*)&fwL2[e*66 + j2*2] = *(const float2*)&fw2[e*64 + j2*2];
  }
  // crow -> sCROW (float4)
  for (int idx = tid; idx < 190; idx += 512) {
    int k = idx / 95, r4 = idx % 95;
    *(float4*)&sCROW[k*380 + r4*4] =
        *(const float4*)&crow[(size_t)(k*BS + b)*380 + r4*4];
  }
  if (tid < STEPS*8) {
    int s = tid >> 3, l = tid & 7;
    float d = fabsf((float)(timeq[b*TT + s + l] - timeq[b*TT + s + 8]));
    sED[tid] = expf(-logf(d + 1e-6f) * 0.6213349345596119f);
  }
  __syncthreads();                 // sSK / weights visible

  // h0: scatter-init restricted to tracked positions
  for (int idx = tid; idx < 32*64; idx += 512) {
    int p = idx >> 6, e = idx & 63;
    ushort_t hv = 0;
    if (p < 20) {
      int node = sSK[p];
      int lstar = -1;
      #pragma unroll
      for (int l = 0; l < 8; ++l) if (sSK[l] == node) lstar = l;
      if (lstar >= 0) {
        float lp = (label[b*TT + lstar] == 1) ? 1.f : -1.f;
        hv = f2bf(nemb[node*EE + e] * lp);
      }
    }
    sH[p*72 + e] = hv;
  }
  __syncthreads();

  // constant-per-thread fragments
  bfrag8 wb0 = *(const bfrag8*)&sWb[epos*72 + q*8];
  bfrag8 wb1 = *(const bfrag8*)&sWb[epos*72 + 32 + q*8];
  bfrag8 wa0 = *(const bfrag8*)&sWa[epos*72 + q*8];
  bfrag8 wa1 = *(const bfrag8*)&sWa[epos*72 + 32 + q*8];
  bfrag8 w200 = *(const bfrag8*)&sW2[(0*16+nn)*72 + q*8];
  bfrag8 w201 = *(const bfrag8*)&sW2[(0*16+nn)*72 + 32 + q*8];
  bfrag8 w210 = *(const bfrag8*)&sW2[(1*16+nn)*72 + q*8];
  bfrag8 w211 = *(const bfrag8*)&sW2[(1*16+nn)*72 + 32 + q*8];
  bfrag8 w220 = *(const bfrag8*)&sW2[(2*16+nn)*72 + q*8];
  bfrag8 w221 = *(const bfrag8*)&sW2[(2*16+nn)*72 + 32 + q*8];
  bfrag8 w230 = *(const bfrag8*)&sW2[(3*16+nn)*72 + q*8];
  bfrag8 w231 = *(const bfrag8*)&sW2[(3*16+nn)*72 + 32 + q*8];
  float b1v = b1[epos];
  float b2v0 = b2[nn], b2v1 = b2[16+nn], b2v2 = b2[32+nn], b2v3 = b2[48+nn];
  const bfrag8 ZB = {0,0,0,0,0,0,0,0};

  for (int t = 0; t < STEPS; ++t) {
    int p0 = (t == 11) ? 19 : t + 1;
    int R  = (t == 11) ? 1  : 19 - t;
    int ntiles = (R + 1) >> 1;

    // ---- phase A: GEMM1 -> sTV (v rows 0..19), sTU (u rows 0..7)
    if (half == 0) {
      bfrag8 a0 = *(const bfrag8*)&sH[nn*72 + q*8];
      bfrag8 a1 = *(const bfrag8*)&sH[nn*72 + 32 + q*8];
      f32x4 accV = {0,0,0,0};
      accV = MFMA16(a0, wb0, accV);
      accV = MFMA16(a1, wb1, accV);
      int ur = (nn < 8) ? (t + nn) : 24;           // rows 24.. are zero
      bfrag8 u0 = *(const bfrag8*)&sH[ur*72 + q*8];
      bfrag8 u1 = *(const bfrag8*)&sH[ur*72 + 32 + q*8];
      f32x4 accU = {0,0,0,0};
      accU = MFMA16(u0, wa0, accU);
      accU = MFMA16(u1, wa1, accU);
      #pragma unroll
      for (int r = 0; r < 4; ++r)
        sTV[(q*4 + r)*72 + epos] = tanh_fast(accV[r]);
      if (q < 2) {
        #pragma unroll
        for (int r = 0; r < 4; ++r)
          sTU[(q*4 + r)*72 + epos] = tanh_fast(accU[r] + b1v);
      }
    } else {
      bfrag8 a0 = *(const bfrag8*)&sH[(16 + nn)*72 + q*8];
      bfrag8 a1 = *(const bfrag8*)&sH[(16 + nn)*72 + 32 + q*8];
      f32x4 accV = {0,0,0,0};
      accV = MFMA16(a0, wb0, accV);
      accV = MFMA16(a1, wb1, accV);
      if (q == 0) {
        #pragma unroll
        for (int r = 0; r < 4; ++r)
          sTV[(16 + r)*72 + epos] = tanh_fast(accV[r]);
      }
    }
    __syncthreads();

    // ---- phase B: per-warp whole tiles, in-register Pade -> MFMA -> epilogue
    for (int rt = w; rt < ntiles; rt += 8) {
      int i = rt*2 + (nn >> 3);       // A-row block (relative p index)
      int lA = nn & 7;
      bfrag8 a0 = ZB, a1 = ZB;
      if (i < R) {
        int p = p0 + i;
        const float2* tvlo = (const float2*)&sTV[p*72 + q*8];
        const float2* tvhi = (const float2*)&sTV[p*72 + 32 + q*8];
        const float2* tulo = (const float2*)&sTU[lA*72 + q*8];
        const float2* tuhi = (const float2*)&sTU[lA*72 + 32 + q*8];
        union { bfrag8 v; __hip_bfloat162 h[4]; } A0, A1;
        #pragma unroll
        for (int j = 0; j < 4; ++j) {
          A0.h[j] = pade2(tvlo[j], tulo[j]);
          A1.h[j] = pade2(tvhi[j], tuhi[j]);
        }
        a0 = A0.v; a1 = A1.v;
      }
      f32x4 z0 = {0,0,0,0}, z1 = {0,0,0,0}, z2 = {0,0,0,0}, z3 = {0,0,0,0};
      z0 = MFMA16(a0, w200, z0);  z0 = MFMA16(a1, w201, z0);
      z1 = MFMA16(a0, w210, z1);  z1 = MFMA16(a1, w211, z1);
      z2 = MFMA16(a0, w220, z2);  z2 = MFMA16(a1, w221, z2);
      z3 = MFMA16(a0, w230, z3);  z3 = MFMA16(a1, w231, z3);

      int pi = rt*2 + (q >> 1);       // D-row block (relative p index)
      int p = p0 + pi;
      int psafe = (pi < R) ? p : p0;  // keep LDS reads in range
      float ag00=0,ag01=0,ag02=0,ag03=0, ag10=0,ag11=0,ag12=0,ag13=0;
      #pragma unroll
      for (int r = 0; r < 4; ++r) {
        int l = (q & 1)*4 + r;
        float c0 = sCROW[(t + l)*20 + psafe];
        float c1 = sCROW[380 + (t + l)*20 + psafe];
        float ed = sED[t*8 + l];
        float m;
        m = tanh_fast(z0[r] + b2v0) * ed; ag00 = fmaf(c0,m,ag00); ag10 = fmaf(c1,m,ag10);
        m = tanh_fast(z1[r] + b2v1) * ed; ag01 = fmaf(c0,m,ag01); ag11 = fmaf(c1,m,ag11);
        m = tanh_fast(z2[r] + b2v2) * ed; ag02 = fmaf(c0,m,ag02); ag12 = fmaf(c1,m,ag12);
        m = tanh_fast(z3[r] + b2v3) * ed; ag03 = fmaf(c0,m,ag03); ag13 = fmaf(c1,m,ag13);
      }
      ag00 += __shfl_xor(ag00,16); ag01 += __shfl_xor(ag01,16);
      ag02 += __shfl_xor(ag02,16); ag03 += __shfl_xor(ag03,16);
      ag10 += __shfl_xor(ag10,16); ag11 += __shfl_xor(ag11,16);
      ag12 += __shfl_xor(ag12,16); ag13 += __shfl_xor(ag13,16);
      if ((q & 1) == 0 && pi < R) {
        sH[p*72 +      nn] = f2bf(0.5f*(ag00 + ag10));
        sH[p*72 + 16 + nn] = f2bf(0.5f*(ag01 + ag11));
        sH[p*72 + 32 + nn] = f2bf(0.5f*(ag02 + ag12));
        sH[p*72 + 48 + nn] = f2bf(0.5f*(ag03 + ag13));
        if (p == t + 8) {
          sAGG[(t*2 + 0)*68 +      nn] = ag00;
          sAGG[(t*2 + 0)*68 + 16 + nn] = ag01;
          sAGG[(t*2 + 0)*68 + 32 + nn] = ag02;
          sAGG[(t*2 + 0)*68 + 48 + nn] = ag03;
          sAGG[(t*2 + 1)*68 +      nn] = ag10;
          sAGG[(t*2 + 1)*68 + 16 + nn] = ag11;
          sAGG[(t*2 + 1)*68 + 32 + nn] = ag12;
          sAGG[(t*2 + 1)*68 + 48 + nn] = ag13;
        }
      }
    }
    __syncthreads();
  }

  // ======================= head (fused pred) =======================
  // 24 tasks = (t,k); task = round*8 + w; weights prestaged in fwL1/fwL2.
  int e = lane;
  float h1s[3];
  float fb1v = fb1[e], g1v = g1[e], be1v = be1[e];
  #pragma unroll
  for (int r3 = 0; r3 < 3; ++r3) {
    int task = r3*8 + w;
    const float* xv = &sAGG[task*68];
    const float2* xv2 = (const float2*)xv;
    const float2* wp  = (const float2*)&fwL1[e*66];
    float x = xv[e];
    float y0 = fb1v, y1 = 0.f;
    #pragma unroll
    for (int j = 0; j < 32; j += 2) {
      float2 a  = xv2[j];     float2 bb = wp[j];
      y0 = fmaf(a.x, bb.x, y0);  y0 = fmaf(a.y, bb.y, y0);
      float2 a2 = xv2[j+1];   float2 b2f = wp[j+1];
      y1 = fmaf(a2.x, b2f.x, y1);  y1 = fmaf(a2.y, b2f.y, y1);
    }
    float h1 = x + lrelu(y0 + y1);
    float mean1 = wsum64(h1) * (1.f/64.f);
    float d1 = h1 - mean1;
    float var1 = wsum64(d1*d1) * (1.f/64.f);
    float xn = d1 * rsqrtf(var1 + 1e-5f) * g1v + be1v;
    sXN[task*68 + e] = xn;
    h1s[r3] = h1;
  }
  __syncthreads();                 // all xn written

  float fb2v = fb2[e], g2v = g2[e], be2v = be2[e];
  float w3a = fw3[e], w3b = fw3[64 + e];
  float fb30 = fb3[0], fb31 = fb3[1];
  #pragma unroll
  for (int r3 = 0; r3 < 3; ++r3) {
    int task = r3*8 + w;
    const float2* xn2v = (const float2*)&sXN[task*68];
    const float2* wp   = (const float2*)&fwL2[e*66];
    float z0 = fb2v, z1 = 0.f;
    #pragma unroll
    for (int j = 0; j < 32; j += 2) {
      float2 a  = xn2v[j];    float2 bb = wp[j];
      z0 = fmaf(a.x, bb.x, z0);  z0 = fmaf(a.y, bb.y, z0);
      float2 a2 = xn2v[j+1];  float2 b2f = wp[j+1];
      z1 = fmaf(a2.x, b2f.x, z1);  z1 = fmaf(a2.y, b2f.y, z1);
    }
    float h2 = h1s[r3] + lrelu(z0 + z1);
    float mean2 = wsum64(h2) * (1.f/64.f);
    float d2 = h2 - mean2;
    float var2 = wsum64(d2*d2) * (1.f/64.f);
    float xn2 = d2 * rsqrtf(var2 + 1e-5f) * g2v + be2v;
    float p0s = wsum64(xn2 * w3a);
    float p1s = wsum64(xn2 * w3b);
    if (e == 0) {
      int ts = task >> 1, kk = task & 1;
      float l0 = p0s + fb30, l1 = p1s + fb31;
      out[(ts*BS + b)*2 + kk] = 1.f / (1.f + expf(l0 - l1));
    }
  }
}

extern "C" void kernel_launch(void* const* d_in, const int* in_sizes, int n_in,
                              void* d_out, int out_size, void* d_ws, size_t ws_size,
                              hipStream_t stream) {
  const int*   skill = (const int*)d_in[0];
  const int*   timeq = (const int*)d_in[1];
  const int*   label = (const int*)d_in[2];
  const float* adj   = (const float*)d_in[3];
  const float* nemb  = (const float*)d_in[4];
  const float* W1    = (const float*)d_in[5];
  const float* b1    = (const float*)d_in[6];
  const float* W2    = (const float*)d_in[7];
  const float* b2    = (const float*)d_in[8];
  float* out = (float*)d_out;

  float* crow = (float*)d_ws;                // 32*19*20 = 12160 floats

  setup_kernel<<<128, 256, 0, stream>>>(skill, adj, crow);
  step_kernel<<<16, 512, 0, stream>>>(skill, timeq, label, nemb, W1, W2,
      b1, b2, crow,
      (const float*)d_in[9],  (const float*)d_in[10],
      (const float*)d_in[11], (const float*)d_in[12],
      (const float*)d_in[13], (const float*)d_in[14],
      (const float*)d_in[15], (const float*)d_in[16],
      (const float*)d_in[17], (const float*)d_in[18], out);
}